// Round 1
// baseline (5126.905 us; speedup 1.0000x reference)
//
#include <hip/hip_runtime.h>
#include <hip/hip_fp16.h>

typedef unsigned int u32;

// ---------------- workspace layout (bytes) ----------------
// region0 (reused):
//   X2   [8192][300] f32 @ 0              (dead after pre-gemm)
//   pre  [8192][4096] f16 @ 9,830,400     (dead after scan)
// overlay after scan (all inside region0):
static constexpr size_t OFF_X2    = 0;
static constexpr size_t OFF_PRE   = 9830400;
static constexpr size_t OFF_TOUT  = 0;          // text_out [32][256][512] f32
static constexpr size_t OFF_TOUTT = 16777216;   // tOutT    [32][512][256] f32
static constexpr size_t OFF_PWT   = 33554432;   // pw_text  [32][256][512] f32
static constexpr size_t OFF_AGG0  = 50331648;   // agg0     [32][256][512] f32
static constexpr size_t OFF_Y     = 76939264;   // y [2][32][256][512] f32
static constexpr size_t OFF_PWX   = 110493696;  // pwx [32][256][512] f32
static constexpr size_t OFF_WD    = 127270912;  // packed fp16 whh, 2 x 512k u32
static constexpr size_t OFF_WIH   = 131465216;  // wihcat [4096][300] f32
static constexpr size_t OFF_BIA   = 136380416;  // biascat [4096] f32
static constexpr size_t OFF_W1T   = 136396800;  // w1T [3][512][512] f32
static constexpr size_t OFF_W2T   = 139542528;  // w2T [3][512][512] f32
static constexpr size_t OFF_META  = 142688256;  // int a0[32],a1[32],nm[32],tl[32]
static constexpr size_t OFF_CLF   = 142688768;  // float cl[32]
static constexpr size_t OFF_DEN   = 142688896;  // denom [32][256] f32
static constexpr size_t OFF_POSW  = 142721664;  // posw  [32][256] f32
static constexpr size_t OFF_AGGM  = 142754432;  // aggm [32][4][512] f32
static constexpr size_t OFF_GMSK  = 143016576;  // gmask [32][4][512] f32
static constexpr size_t OFF_C1PW  = 143278720;  // c1pw [32][6][512] f32
static constexpr size_t OFF_XC2   = 143671936;  // xc2 [32][4][512] f32
static constexpr size_t OFF_AVEC  = 143934080;  // avec [3][32][512] f32
static constexpr size_t WS_NEED   = 144130688;

__device__ __forceinline__ float sigf(float x) { return 1.f / (1.f + expf(-x)); }
__device__ __forceinline__ float cvtlo(u32 w) { return __half2float(__ushort_as_half((unsigned short)(w & 0xffffu))); }
__device__ __forceinline__ float cvthi(u32 w) { return __half2float(__ushort_as_half((unsigned short)(w >> 16))); }

// ---------------- lengths / meta ----------------
__global__ void len_k(const int* __restrict__ ti, const int* __restrict__ ai,
                      const int* __restrict__ li, int* __restrict__ meta, float* __restrict__ clf)
{
    int b = threadIdx.x;
    if (b >= 32) return;
    int tl = 0;
    for (int s = 0; s < 256; ++s) tl += (ti[b*256+s] != 0);
    int al = 0;
    for (int i = 0; i < 4; ++i) al += (ai[b*4+i] != 0);
    int ll = 0;
    for (int i = 0; i < 16; ++i) ll += (li[b*16+i] != 0);
    meta[b]      = ll;            // a0
    meta[32+b]   = ll + al - 1;   // a1
    meta[64+b]   = al;            // nmask
    meta[96+b]   = tl;            // text_len
    clf[b] = (float)(tl - al);
}

// ---------------- denom + pos-weight ----------------
__global__ __launch_bounds__(256)
void pd_k(const float* __restrict__ adj, const int* __restrict__ meta,
          const float* __restrict__ clf, float* __restrict__ denom, float* __restrict__ posw)
{
    int row = blockIdx.x;            // b*256+s
    int b = row >> 8, s = row & 255;
    int tid = threadIdx.x;
    float v = adj[(size_t)row*256 + tid];
    #pragma unroll
    for (int off = 1; off < 64; off <<= 1) v += __shfl_xor(v, off);
    __shared__ float rd[4];
    if ((tid & 63) == 0) rd[tid >> 6] = v;
    __syncthreads();
    if (tid == 0) {
        denom[row] = rd[0] + rd[1] + rd[2] + rd[3] + 1.f;
        int a0 = meta[b], a1 = meta[32+b], tl = meta[96+b];
        float cl = clf[b];
        float w;
        if (s < a0)       w = 1.f - (float)(a0 - s) / cl;
        else if (s <= a1) w = 0.f;
        else if (s < tl)  w = 1.f - (float)(s - a1) / cl;
        else              w = 0.f;
        posw[row] = w;
    }
}

// ---------------- embedding gather: X2[s][b][e] ----------------
__global__ __launch_bounds__(128)
void gather_k(const int* __restrict__ ti, const float* __restrict__ emb, float* __restrict__ X2)
{
    int row = blockIdx.x;            // s*32+b
    int b = row & 31, s = row >> 5;
    int idx = ti[b*256 + s];
    const float* e = emb + (size_t)idx*300;
    float* o = X2 + (size_t)row*300;
    for (int k = threadIdx.x; k < 300; k += 128) o[k] = e[k];
}

// ---------------- pack whh -> fp16, scan-friendly layout ----------------
// u32 at ((q*1024 + t)*4 + c): lo = f16(whh[2t][4q+c]), hi = f16(whh[2t+1][4q+c])
__global__ __launch_bounds__(256)
void wdpack_k(const float* __restrict__ wf, const float* __restrict__ wb, u32* __restrict__ Wd)
{
    u32 idx = blockIdx.x*256 + threadIdx.x;   // < 1,048,576
    int dir = idx >> 19;
    u32 r = idx & 524287u;
    int c = r & 3;
    int t = (r >> 2) & 1023;
    int q = r >> 12;
    int k = 4*q + c;
    const float* w = dir ? wb : wf;
    float v0 = w[(size_t)(2*t)*512 + k];
    float v1 = w[(size_t)(2*t+1)*512 + k];
    u32 u = (u32)__half_as_ushort(__float2half(v0)) | ((u32)__half_as_ushort(__float2half(v1)) << 16);
    Wd[idx] = u;
}

// ---------------- conv weight transpose: wT[k][i][o] = w[o][i][k] ----------------
__global__ __launch_bounds__(256)
void wtrans_k(const float* __restrict__ w1, const float* __restrict__ w2,
              float* __restrict__ w1T, float* __restrict__ w2T)
{
    u32 idx = blockIdx.x*256 + threadIdx.x;   // < 786432
    const float* src = blockIdx.y ? w2 : w1;
    float* dst = blockIdx.y ? w2T : w1T;
    int k = idx >> 18;
    int i = (idx >> 9) & 511;
    int o = idx & 511;
    dst[idx] = src[((size_t)o*512 + i)*3 + k];
}

// ---------------- generic f32 tiled GEMM, 128x128, 8x8/thread ----------------
// MODE 0: C=f16, +bias     MODE 1: C=f32 plain     MODE 2: C=f32, relu(acc/denom[m]+bias[n])*posw[m]
// BT: B stored (N,K) row-major; else (K,N)
template<int MODE, bool BT>
__global__ __launch_bounds__(256)
void gemm_k(const float* __restrict__ A, const float* __restrict__ B,
            void* __restrict__ C, int M, int N, int K,
            long sA, long sB, long sC,
            const float* __restrict__ bias,
            const float* __restrict__ denom,
            const float* __restrict__ posw)
{
    __shared__ float As[32][132];
    __shared__ float Bs[32][132];
    const int z = blockIdx.z;
    A += (size_t)z * sA;
    B += (size_t)z * sB;
    const int m0 = blockIdx.x * 128;
    const int n0 = blockIdx.y * 128;
    const int tid = threadIdx.x;
    const int tx = tid & 15, ty = tid >> 4;
    float acc[8][8];
    #pragma unroll
    for (int i = 0; i < 8; ++i)
        #pragma unroll
        for (int j = 0; j < 8; ++j) acc[i][j] = 0.f;
    const int nkb = (K + 31) >> 5;
    for (int kb = 0; kb < nkb; ++kb) {
        const int k0 = kb << 5;
        #pragma unroll
        for (int rep = 0; rep < 4; ++rep) {
            int idx = rep*256 + tid;
            int row = idx >> 3;
            int c4 = (idx & 7) << 2;
            int gk = k0 + c4;
            const float* ap = A + (size_t)(m0 + row)*K + gk;
            float4 v;
            if (gk + 3 < K) v = *(const float4*)ap;
            else {
                v.x = (gk   < K) ? ap[0] : 0.f;
                v.y = (gk+1 < K) ? ap[1] : 0.f;
                v.z = (gk+2 < K) ? ap[2] : 0.f;
                v.w = (gk+3 < K) ? ap[3] : 0.f;
            }
            As[c4+0][row] = v.x; As[c4+1][row] = v.y;
            As[c4+2][row] = v.z; As[c4+3][row] = v.w;
        }
        if (BT) {
            #pragma unroll
            for (int rep = 0; rep < 4; ++rep) {
                int idx = rep*256 + tid;
                int row = idx >> 3;
                int c4 = (idx & 7) << 2;
                int gk = k0 + c4;
                const float* bp = B + (size_t)(n0 + row)*K + gk;
                float4 v;
                if (gk + 3 < K) v = *(const float4*)bp;
                else {
                    v.x = (gk   < K) ? bp[0] : 0.f;
                    v.y = (gk+1 < K) ? bp[1] : 0.f;
                    v.z = (gk+2 < K) ? bp[2] : 0.f;
                    v.w = (gk+3 < K) ? bp[3] : 0.f;
                }
                Bs[c4+0][row] = v.x; Bs[c4+1][row] = v.y;
                Bs[c4+2][row] = v.z; Bs[c4+3][row] = v.w;
            }
        } else {
            #pragma unroll
            for (int rep = 0; rep < 4; ++rep) {
                int idx = rep*256 + tid;
                int kk = idx >> 5;
                int nn = (idx & 31) << 2;
                int gk = k0 + kk;
                float4 v = make_float4(0.f, 0.f, 0.f, 0.f);
                if (gk < K) v = *(const float4*)(B + (size_t)gk*N + n0 + nn);
                *(float4*)&Bs[kk][nn] = v;
            }
        }
        __syncthreads();
        #pragma unroll
        for (int k = 0; k < 32; ++k) {
            float a[8], br[8];
            *(float4*)&a[0]  = *(const float4*)&As[k][ty*8];
            *(float4*)&a[4]  = *(const float4*)&As[k][ty*8+4];
            *(float4*)&br[0] = *(const float4*)&Bs[k][tx*8];
            *(float4*)&br[4] = *(const float4*)&Bs[k][tx*8+4];
            #pragma unroll
            for (int i = 0; i < 8; ++i)
                #pragma unroll
                for (int j = 0; j < 8; ++j)
                    acc[i][j] = fmaf(a[i], br[j], acc[i][j]);
        }
        __syncthreads();
    }
    if (MODE == 0) {
        __half* cp = (__half*)C + (size_t)z*sC;
        #pragma unroll
        for (int i = 0; i < 8; ++i) {
            size_t ro = (size_t)(m0 + ty*8 + i)*N;
            #pragma unroll
            for (int j = 0; j < 8; j += 2) {
                int n = n0 + tx*8 + j;
                __half2 hv = __halves2half2(__float2half(acc[i][j] + bias[n]),
                                            __float2half(acc[i][j+1] + bias[n+1]));
                *(__half2*)(cp + ro + n) = hv;
            }
        }
    } else if (MODE == 1) {
        float* cp = (float*)C + (size_t)z*sC;
        #pragma unroll
        for (int i = 0; i < 8; ++i) {
            size_t ro = (size_t)(m0 + ty*8 + i)*N + n0 + tx*8;
            *(float4*)(cp + ro)     = make_float4(acc[i][0], acc[i][1], acc[i][2], acc[i][3]);
            *(float4*)(cp + ro + 4) = make_float4(acc[i][4], acc[i][5], acc[i][6], acc[i][7]);
        }
    } else {
        float* cp = (float*)C + (size_t)z*sC;
        #pragma unroll
        for (int i = 0; i < 8; ++i) {
            int m = m0 + ty*8 + i;
            float inv = 1.f / denom[m];
            float pw = posw[m];
            size_t ro = (size_t)m*N + n0 + tx*8;
            #pragma unroll
            for (int j = 0; j < 8; ++j) {
                float v = fmaf(acc[i][j], inv, bias[n0 + tx*8 + j]);
                cp[ro + j] = fmaxf(v, 0.f) * pw;
            }
        }
    }
}

// ---------------- LSTM scan: one WG per (batch, dir), zero sync ----------------
__global__ __launch_bounds__(1024)
void lstm_scan_k(const __half* __restrict__ pre, const u32* __restrict__ Wd,
                 const int* __restrict__ ti, float* __restrict__ y)
{
    __shared__ float h_lds[512];
    __shared__ float c_lds[512];
    __shared__ float gates[2048];
    int bid = blockIdx.x;
    int x = bid & 7, g = bid >> 3;
    int dir = x >> 2;
    int b = (x & 3)*8 + g;
    int tid = threadIdx.x;
    if (tid < 512) { h_lds[tid] = 0.f; c_lds[tid] = 0.f; }
    __syncthreads();
    const uint4* W4 = (const uint4*)(Wd + (size_t)dir*524288);
    float* yb = y + ((size_t)dir*32 + b)*256*512;
    for (int t = 0; t < 256; ++t) {
        int s = dir ? (255 - t) : t;
        const __half* prow = pre + ((size_t)s*32 + b)*4096 + (size_t)dir*2048;
        u32 p2 = *(const u32*)(prow + 2*tid);
        float acc0 = cvtlo(p2);
        float acc1 = cvthi(p2);
        const uint4* wp = W4 + tid;
        #pragma unroll 4
        for (int q = 0; q < 128; ++q) {
            uint4 w = wp[q*1024];
            float4 h4 = *(const float4*)&h_lds[4*q];
            acc0 = fmaf(cvtlo(w.x), h4.x, acc0); acc1 = fmaf(cvthi(w.x), h4.x, acc1);
            acc0 = fmaf(cvtlo(w.y), h4.y, acc0); acc1 = fmaf(cvthi(w.y), h4.y, acc1);
            acc0 = fmaf(cvtlo(w.z), h4.z, acc0); acc1 = fmaf(cvthi(w.z), h4.z, acc1);
            acc0 = fmaf(cvtlo(w.w), h4.w, acc0); acc1 = fmaf(cvthi(w.w), h4.w, acc1);
        }
        *(float2*)&gates[2*tid] = make_float2(acc0, acc1);
        __syncthreads();
        if (tid < 512) {
            float gi = gates[tid], gf = gates[512+tid], gc = gates[1024+tid], go = gates[1536+tid];
            float co = c_lds[tid];
            float cn = sigf(gf)*co + sigf(gi)*tanhf(gc);
            float hn = sigf(go)*tanhf(cn);
            bool mk = (ti[b*256 + s] != 0);
            yb[(size_t)s*512 + tid] = mk ? hn : 0.f;
            h_lds[tid] = mk ? hn : h_lds[tid];
            c_lds[tid] = mk ? cn : co;
        }
        __syncthreads();
    }
}

// ---------------- combine: pairwise-mean + pos-weight ----------------
__global__ __launch_bounds__(256)
void combine_k(const float* __restrict__ y, const float* __restrict__ posw,
               float* __restrict__ text_out, float* __restrict__ pw_text)
{
    size_t idx = (size_t)blockIdx.x*256 + threadIdx.x;   // < 4,194,304
    int hh = (int)(idx & 511);
    size_t rem = idx >> 9;
    int s = (int)(rem & 255);
    int b = (int)(rem >> 8);
    const float* p;
    if (hh < 256) p = y + (((size_t)b*256 + s)*512 + 2*hh);
    else          p = y + (((size_t)(32 + b)*256 + s)*512 + 2*(hh - 256));
    float v = 0.5f*(p[0] + p[1]);
    text_out[idx] = v;
    pw_text[idx] = v * posw[b*256 + s];
}

// ---------------- transpose text_out -> tOutT[b][h][s] ----------------
__global__ __launch_bounds__(256)
void transp_k(const float* __restrict__ text_out, float* __restrict__ tOutT)
{
    __shared__ float tile[32][33];
    int b = blockIdx.z, s0 = blockIdx.x*32, h0 = blockIdx.y*32;
    int tx = threadIdx.x & 31, ty4 = threadIdx.x >> 5;
    #pragma unroll
    for (int rr = 0; rr < 4; ++rr) {
        int sy = ty4 + rr*8;
        tile[sy][tx] = text_out[((size_t)b*256 + s0 + sy)*512 + h0 + tx];
    }
    __syncthreads();
    #pragma unroll
    for (int rr = 0; rr < 4; ++rr) {
        int hy = ty4 + rr*8;
        tOutT[((size_t)b*512 + h0 + hy)*256 + s0 + tx] = tile[tx][hy];
    }
}

// ---------------- masked-row adj aggregation: aggm[b][r] = adj[b][a0+r] @ pwx[b] ----------------
__global__ __launch_bounds__(256)
void aggm_k(const float* __restrict__ adj, const float* __restrict__ pwx,
            const int* __restrict__ meta, float* __restrict__ aggm)
{
    int b = blockIdx.x >> 2, r = blockIdx.x & 3;
    int a0 = meta[b], nm = meta[64+b];
    int s = a0 + r; if (s > 255) s = 255;
    __shared__ float arow[256];
    int tid = threadIdx.x;
    arow[tid] = adj[((size_t)b*256 + s)*256 + tid];
    __syncthreads();
    float acc0 = 0.f, acc1 = 0.f;
    for (int t = 0; t < 256; ++t) {
        float av = arow[t];
        acc0 = fmaf(av, pwx[((size_t)b*256 + t)*512 + tid], acc0);
        acc1 = fmaf(av, pwx[((size_t)b*256 + t)*512 + tid + 256], acc1);
    }
    bool ok = (r < nm);
    aggm[((size_t)b*4 + r)*512 + tid]       = ok ? acc0 : 0.f;
    aggm[((size_t)b*4 + r)*512 + tid + 256] = ok ? acc1 : 0.f;
}

// ---------------- graph_mask: sum_k relu((aggm @ w_k)/denom + b_k), masked rows ----------------
__global__ __launch_bounds__(256)
void gmask_k(const float* __restrict__ aggm, const float* __restrict__ gcw,
             const float* __restrict__ gcb, const int* __restrict__ meta,
             const float* __restrict__ denom, float* __restrict__ gmsk)
{
    int b = blockIdx.x >> 2, r = blockIdx.x & 3;
    int a0 = meta[b], nm = meta[64+b];
    __shared__ float rowv[512];
    int tid = threadIdx.x;
    rowv[tid]       = aggm[((size_t)b*4 + r)*512 + tid];
    rowv[tid + 256] = aggm[((size_t)b*4 + r)*512 + tid + 256];
    __syncthreads();
    float acc0 = 0.f, acc1 = 0.f;
    if (r < nm) {
        int srow = a0 + r; if (srow > 255) srow = 255;
        float inv = 1.f / denom[b*256 + srow];
        for (int kk = 1; kk <= 5; ++kk) {
            const float* w = gcw + (size_t)kk*262144;
            const float* bb = gcb + kk*512;
            float s0 = 0.f, s1 = 0.f;
            for (int j = 0; j < 512; ++j) {
                float rv = rowv[j];
                s0 = fmaf(rv, w[(size_t)j*512 + tid], s0);
                s1 = fmaf(rv, w[(size_t)j*512 + tid + 256], s1);
            }
            acc0 += fmaxf(fmaf(s0, inv, bb[tid]), 0.f);
            acc1 += fmaxf(fmaf(s1, inv, bb[tid+256]), 0.f);
        }
    }
    gmsk[((size_t)b*4 + r)*512 + tid]       = acc0;
    gmsk[((size_t)b*4 + r)*512 + tid + 256] = acc1;
}

// ---------------- conv1 on 6 needed rows, output already relu'd and pos-weighted ----------------
__global__ __launch_bounds__(256)
void conv1_k(const float* __restrict__ pwt, const float* __restrict__ w1T,
             const float* __restrict__ b1, const int* __restrict__ meta,
             const float* __restrict__ posw, float* __restrict__ c1pw)
{
    int b = blockIdx.x / 6, r = blockIdx.x % 6;
    int a0 = meta[b];
    int s = a0 - 1 + r;
    __shared__ float xin[3][512];
    int tid = threadIdx.x;
    #pragma unroll
    for (int kk = 0; kk < 3; ++kk) {
        int si = s - 1 + kk;
        float v0 = 0.f, v1 = 0.f;
        if (si >= 0 && si < 256) {
            v0 = pwt[((size_t)b*256 + si)*512 + tid];
            v1 = pwt[((size_t)b*256 + si)*512 + tid + 256];
        }
        xin[kk][tid] = v0; xin[kk][tid+256] = v1;
    }
    __syncthreads();
    float acc0 = b1[tid], acc1 = b1[tid+256];
    for (int kk = 0; kk < 3; ++kk)
        for (int j = 0; j < 512; ++j) {
            float xv = xin[kk][j];
            acc0 = fmaf(xv, w1T[((size_t)kk*512 + j)*512 + tid], acc0);
            acc1 = fmaf(xv, w1T[((size_t)kk*512 + j)*512 + tid + 256], acc1);
        }
    bool valid = (s >= 0 && s < 256);
    float pv = valid ? posw[b*256 + s] : 0.f;
    c1pw[((size_t)b*6 + r)*512 + tid]       = valid ? fmaxf(acc0, 0.f)*pv : 0.f;
    c1pw[((size_t)b*6 + r)*512 + tid + 256] = valid ? fmaxf(acc1, 0.f)*pv : 0.f;
}

// ---------------- conv2 on 4 needed rows ----------------
__global__ __launch_bounds__(256)
void conv2_k(const float* __restrict__ c1pw, const float* __restrict__ w2T,
             const float* __restrict__ b2, const int* __restrict__ meta,
             float* __restrict__ xc2)
{
    int b = blockIdx.x >> 2, r = blockIdx.x & 3;
    int nm = meta[64+b];
    __shared__ float xin[3][512];
    int tid = threadIdx.x;
    #pragma unroll
    for (int kk = 0; kk < 3; ++kk) {
        xin[kk][tid]       = c1pw[((size_t)b*6 + r + kk)*512 + tid];
        xin[kk][tid + 256] = c1pw[((size_t)b*6 + r + kk)*512 + tid + 256];
    }
    __syncthreads();
    float acc0 = b2[tid], acc1 = b2[tid+256];
    for (int kk = 0; kk < 3; ++kk)
        for (int j = 0; j < 512; ++j) {
            float xv = xin[kk][j];
            acc0 = fmaf(xv, w2T[((size_t)kk*512 + j)*512 + tid], acc0);
            acc1 = fmaf(xv, w2T[((size_t)kk*512 + j)*512 + tid + 256], acc1);
        }
    bool ok = (r < nm);
    xc2[((size_t)b*4 + r)*512 + tid]       = ok ? fmaxf(acc0, 0.f) : 0.f;
    xc2[((size_t)b*4 + r)*512 + tid + 256] = ok ? fmaxf(acc1, 0.f) : 0.f;
}

// ---------------- multi-hop attend: 4 masked rows + 1 shared outside row ----------------
__global__ __launch_bounds__(512)
void attend_k(const float* __restrict__ text_out, const float* __restrict__ tOutT,
              const float* __restrict__ gmsk, const float* __restrict__ xc2,
              const int* __restrict__ meta,
              const float* __restrict__ lng, const float* __restrict__ lnb,
              float* __restrict__ avec)
{
    __shared__ float m5[5][512];
    __shared__ float alpha[5][256];
    __shared__ float apart[5][256];
    __shared__ float wt[256];
    __shared__ float msum[512];
    __shared__ float red[8];
    int b = blockIdx.x, att = blockIdx.y;
    int tid = threadIdx.x;
    int a0 = meta[b], nm = meta[64+b];
    #pragma unroll
    for (int r = 0; r < 4; ++r) {
        float v = 0.f;
        if (r < nm) {
            if (att == 0)      v = gmsk[((size_t)b*4 + r)*512 + tid];
            else if (att == 1) v = text_out[((size_t)b*256 + a0 + r)*512 + tid];
            else               v = xc2[((size_t)b*4 + r)*512 + tid];
        }
        m5[r][tid] = v;
    }
    m5[4][tid] = 0.f;
    const float* tT = tOutT + (size_t)b*512*256;
    const float* tO = text_out + (size_t)b*256*512;
    float lgam = lng[att*512 + tid], lbet = lnb[att*512 + tid];
    __syncthreads();
    for (int hop = 0; hop < 9; ++hop) {
        // phase 1: alpha[r][t] = sum_h m5[r][h] * tOut[t][h]
        {
            int t = tid & 255, hf = tid >> 8;
            float a5[5] = {0.f, 0.f, 0.f, 0.f, 0.f};
            const float* tp = tT + (size_t)(hf*256)*256 + t;
            for (int h = 0; h < 256; ++h) {
                float v = tp[(size_t)h*256];
                int hh = hf*256 + h;
                #pragma unroll
                for (int r = 0; r < 5; ++r) a5[r] = fmaf(m5[r][hh], v, a5[r]);
            }
            if (hf == 0) { for (int r = 0; r < 5; ++r) alpha[r][t] = a5[r]; }
            else         { for (int r = 0; r < 5; ++r) apart[r][t] = a5[r]; }
        }
        __syncthreads();
        for (int idx = tid; idx < 1280; idx += 512) {
            int r = idx >> 8, t2 = idx & 255;
            alpha[r][t2] += apart[r][t2];
        }
        __syncthreads();
        // phase 2: a[r][hh] = sum_t alpha[r][t] * tOut[t][hh]
        float a5[5] = {0.f, 0.f, 0.f, 0.f, 0.f};
        for (int t = 0; t < 256; ++t) {
            float v = tO[(size_t)t*512 + tid];
            #pragma unroll
            for (int r = 0; r < 5; ++r) a5[r] = fmaf(alpha[r][t], v, a5[r]);
        }
        // LN(sigmoid(a)) update, two-pass variance
        #pragma unroll 1
        for (int r = 0; r < 5; ++r) {
            float xv = sigf(a5[r]);
            float s1 = xv;
            #pragma unroll
            for (int off = 1; off < 64; off <<= 1) s1 += __shfl_xor(s1, off);
            if ((tid & 63) == 0) red[tid >> 6] = s1;
            __syncthreads();
            float mu = (red[0]+red[1]+red[2]+red[3]+red[4]+red[5]+red[6]+red[7]) * (1.f/512.f);
            __syncthreads();
            float d = xv - mu;
            float s2 = d*d;
            #pragma unroll
            for (int off = 1; off < 64; off <<= 1) s2 += __shfl_xor(s2, off);
            if ((tid & 63) == 0) red[tid >> 6] = s2;
            __syncthreads();
            float var = (red[0]+red[1]+red[2]+red[3]+red[4]+red[5]+red[6]+red[7]) * (1.f/512.f);
            __syncthreads();
            float ln = d * rsqrtf(var + 1e-12f) * lgam + lbet;
            if (r < nm || r == 4) m5[r][tid] += 0.01f * ln;
        }
        __syncthreads();
    }
    // final: msum, scores, softmax, weighted avg
    {
        float ms = 0.f;
        #pragma unroll
        for (int r = 0; r < 4; ++r) if (r < nm) ms += m5[r][tid];
        ms += (float)(256 - nm) * m5[4][tid];
        msum[tid] = ms;
    }
    __syncthreads();
    {
        int t = tid & 255, hf = tid >> 8;
        float sc = 0.f;
        const float* tp = tT + (size_t)(hf*256)*256 + t;
        for (int h = 0; h < 256; ++h) sc = fmaf(msum[hf*256 + h], tp[(size_t)h*256], sc);
        if (hf == 0) alpha[0][t] = sc; else apart[0][t] = sc;
    }
    __syncthreads();
    float sv = (tid < 256) ? (alpha[0][tid] + apart[0][tid]) : -3.0e38f;
    float mx = sv;
    #pragma unroll
    for (int off = 1; off < 64; off <<= 1) mx = fmaxf(mx, __shfl_xor(mx, off));
    if ((tid & 63) == 0) red[tid >> 6] = mx;
    __syncthreads();
    mx = fmaxf(fmaxf(fmaxf(red[0], red[1]), fmaxf(red[2], red[3])),
               fmaxf(fmaxf(red[4], red[5]), fmaxf(red[6], red[7])));
    __syncthreads();
    float ex = (tid < 256) ? expf(sv - mx) : 0.f;
    float ss = ex;
    #pragma unroll
    for (int off = 1; off < 64; off <<= 1) ss += __shfl_xor(ss, off);
    if ((tid & 63) == 0) red[tid >> 6] = ss;
    __syncthreads();
    float tot = red[0]+red[1]+red[2]+red[3]+red[4]+red[5]+red[6]+red[7];
    __syncthreads();
    if (tid < 256) wt[tid] = ex / tot;
    __syncthreads();
    float acc = 0.f;
    for (int t = 0; t < 256; ++t) acc = fmaf(wt[t], tO[(size_t)t*512 + tid], acc);
    avec[((size_t)att*32 + b)*512 + tid] = acc;
}

// ---------------- final FC ----------------
__global__ __launch_bounds__(128)
void final_k(const float* __restrict__ avec, const float* __restrict__ fw,
             const float* __restrict__ fbb, float* __restrict__ out)
{
    int b = blockIdx.x, tid = threadIdx.x;
    float a0 = 0.f, a1 = 0.f, a2 = 0.f;
    for (int j = tid; j < 1536; j += 128) {
        float v = avec[((size_t)(j >> 9)*32 + b)*512 + (j & 511)];
        a0 = fmaf(v, fw[j], a0);
        a1 = fmaf(v, fw[1536 + j], a1);
        a2 = fmaf(v, fw[3072 + j], a2);
    }
    #pragma unroll
    for (int off = 1; off < 64; off <<= 1) {
        a0 += __shfl_xor(a0, off); a1 += __shfl_xor(a1, off); a2 += __shfl_xor(a2, off);
    }
    __shared__ float red[6];
    if ((tid & 63) == 0) { int w = tid >> 6; red[w] = a0; red[2+w] = a1; red[4+w] = a2; }
    __syncthreads();
    if (tid == 0) {
        out[b*3+0] = red[0] + red[1] + fbb[0];
        out[b*3+1] = red[2] + red[3] + fbb[1];
        out[b*3+2] = red[4] + red[5] + fbb[2];
    }
}

extern "C" void kernel_launch(void* const* d_in, const int* in_sizes, int n_in,
                              void* d_out, int out_size, void* d_ws, size_t ws_size,
                              hipStream_t stream)
{
    (void)in_sizes; (void)n_in; (void)out_size;
    if (ws_size < WS_NEED) return;
    const int*   ti    = (const int*)d_in[0];
    const int*   ai    = (const int*)d_in[1];
    const int*   li    = (const int*)d_in[2];
    const float* adj   = (const float*)d_in[3];
    const float* emb   = (const float*)d_in[4];
    const float* wih_f = (const float*)d_in[5];
    const float* whh_f = (const float*)d_in[6];
    const float* b_f   = (const float*)d_in[7];
    const float* wih_b = (const float*)d_in[8];
    const float* whh_b = (const float*)d_in[9];
    const float* b_b   = (const float*)d_in[10];
    const float* gcw   = (const float*)d_in[11];
    const float* gcb   = (const float*)d_in[12];
    const float* c1w   = (const float*)d_in[13];
    const float* c1b   = (const float*)d_in[14];
    const float* c2w   = (const float*)d_in[15];
    const float* c2b   = (const float*)d_in[16];
    const float* fw    = (const float*)d_in[17];
    const float* fb    = (const float*)d_in[18];
    const float* lng   = (const float*)d_in[19];
    const float* lnb   = (const float*)d_in[20];

    char* ws = (char*)d_ws;
    float*  X2       = (float*)(ws + OFF_X2);
    __half* pre      = (__half*)(ws + OFF_PRE);
    float*  text_out = (float*)(ws + OFF_TOUT);
    float*  tOutT    = (float*)(ws + OFF_TOUTT);
    float*  pw_text  = (float*)(ws + OFF_PWT);
    float*  agg0     = (float*)(ws + OFF_AGG0);
    float*  y        = (float*)(ws + OFF_Y);
    float*  pwx      = (float*)(ws + OFF_PWX);
    u32*    Wd       = (u32*)(ws + OFF_WD);
    float*  wihcat   = (float*)(ws + OFF_WIH);
    float*  biascat  = (float*)(ws + OFF_BIA);
    float*  w1T      = (float*)(ws + OFF_W1T);
    float*  w2T      = (float*)(ws + OFF_W2T);
    int*    meta     = (int*)(ws + OFF_META);
    float*  clf      = (float*)(ws + OFF_CLF);
    float*  denom    = (float*)(ws + OFF_DEN);
    float*  posw     = (float*)(ws + OFF_POSW);
    float*  aggm     = (float*)(ws + OFF_AGGM);
    float*  gmsk     = (float*)(ws + OFF_GMSK);
    float*  c1pw     = (float*)(ws + OFF_C1PW);
    float*  xc2      = (float*)(ws + OFF_XC2);
    float*  avec     = (float*)(ws + OFF_AVEC);

    len_k<<<1, 64, 0, stream>>>(ti, ai, li, meta, clf);
    pd_k<<<8192, 256, 0, stream>>>(adj, meta, clf, denom, posw);
    gather_k<<<8192, 128, 0, stream>>>(ti, emb, X2);
    wdpack_k<<<4096, 256, 0, stream>>>(whh_f, whh_b, Wd);
    wtrans_k<<<dim3(3072, 2), 256, 0, stream>>>(c1w, c2w, w1T, w2T);
    hipMemcpyAsync(wihcat,          wih_f, (size_t)2048*300*4, hipMemcpyDeviceToDevice, stream);
    hipMemcpyAsync(wihcat + 614400, wih_b, (size_t)2048*300*4, hipMemcpyDeviceToDevice, stream);
    hipMemcpyAsync(biascat,        b_f, 2048*4, hipMemcpyDeviceToDevice, stream);
    hipMemcpyAsync(biascat + 2048, b_b, 2048*4, hipMemcpyDeviceToDevice, stream);

    // pre-activations: [8192 x 4096] = X2 [8192 x 300] @ wihcat^T, +bias, store f16
    gemm_k<0, true><<<dim3(64, 32, 1), 256, 0, stream>>>(X2, wihcat, (void*)pre,
        8192, 4096, 300, 0, 0, 0, biascat, nullptr, nullptr);

    lstm_scan_k<<<64, 1024, 0, stream>>>(pre, Wd, ti, y);
    combine_k<<<16384, 256, 0, stream>>>(y, posw, text_out, pw_text);
    transp_k<<<dim3(8, 16, 32), 256, 0, stream>>>(text_out, tOutT);

    // agg0[b] = adj[b] @ pw_text[b]   (batched)
    gemm_k<1, false><<<dim3(2, 4, 32), 256, 0, stream>>>(adj, pw_text, (void*)agg0,
        256, 512, 256, 65536L, 131072L, 131072L, nullptr, nullptr, nullptr);
    // pwx = posw * relu(agg0 @ gc_w0 / denom + gc_b0)
    gemm_k<2, false><<<dim3(64, 4, 1), 256, 0, stream>>>(agg0, gcw, (void*)pwx,
        8192, 512, 512, 0, 0, 0, gcb, denom, posw);

    aggm_k<<<128, 256, 0, stream>>>(adj, pwx, meta, aggm);
    gmask_k<<<128, 256, 0, stream>>>(aggm, gcw, gcb, meta, denom, gmsk);
    conv1_k<<<192, 256, 0, stream>>>(pw_text, w1T, c1b, meta, posw, c1pw);
    conv2_k<<<128, 256, 0, stream>>>(c1pw, w2T, c2b, meta, xc2);
    attend_k<<<dim3(32, 3), 512, 0, stream>>>(text_out, tOutT, gmsk, xc2, meta, lng, lnb, avec);
    final_k<<<32, 128, 0, stream>>>(avec, fw, fb, (float*)d_out);
}